// Round 5
// baseline (682.330 us; speedup 1.0000x reference)
//
#include <hip/hip_runtime.h>
#include <hip/hip_bf16.h>

// LoRALinear: out = x @ (W + 2.0*B@A)^T + bias ; M=16384, N=4096, K=4096, R=16.
// Round 5: revert to 16x16x32 MFMA (round-2 pattern: measured 0 bank conflicts;
// 32x32 pattern measured +5.03e7 — empirical rule, model TBD). Add:
//  (a) persistent 2x2-quad blocks, grid=256 (1/CU), g-continuous staging
//      pipeline across the 4 tiles (3 of 4 drain/prologue/epilogue exposures
//      removed), XCD-aligned quad mapping (bn-pair per XCD -> B fits its L2);
//  (b) END-0/END-2 barrier drop (isolated rounds 3<->4: -12us, race-analyzed
//      safe: MID's lgkmcnt(0) orders reads before any cross-wave restage).
// ws layout: [0,134217728) x_bf16 ; [134217728, +33554432) W_eff_bf16.

typedef __attribute__((ext_vector_type(8))) short bf16x8;
typedef __attribute__((ext_vector_type(4))) float f32x4;
typedef __attribute__((ext_vector_type(4))) unsigned short u16x4;

#define M_DIM 16384
#define N_DIM 4096
#define K_DIM 4096
#define NT 64   // K-tiles of BK=64 per output tile

__device__ __forceinline__ unsigned short f2bf(float f) {
    unsigned int u = __builtin_bit_cast(unsigned int, f);
    unsigned int r = u + 0x7FFFu + ((u >> 16) & 1u);
    return (unsigned short)(r >> 16);
}

__device__ __forceinline__ void async16(const void* g, void* l) {
    __builtin_amdgcn_global_load_lds(
        (const __attribute__((address_space(1))) unsigned int*)g,
        (__attribute__((address_space(3))) unsigned int*)l,
        16, 0, 0);
}

// ---------------- prep kernel 1: x fp32 -> bf16 ----------------
__global__ void __launch_bounds__(256) cast_x_kernel(
    const float4* __restrict__ x, u16x4* __restrict__ y, int n4) {
    int i = blockIdx.x * blockDim.x + threadIdx.x;
    int stride = gridDim.x * blockDim.x;
    for (; i < n4; i += stride) {
        float4 v = x[i];
        u16x4 o = { f2bf(v.x), f2bf(v.y), f2bf(v.z), f2bf(v.w) };
        y[i] = o;
    }
}

// ---------------- prep kernel 2: W_eff = W + 2*B@A -> bf16 ----------------
__global__ void __launch_bounds__(256) weff_kernel(
    const float* __restrict__ W, const float* __restrict__ lA,
    const float* __restrict__ lB, unsigned short* __restrict__ out) {
    constexpr int K = K_DIM, R = 16;
    constexpr float S = 2.0f;  // 32.0 / 16
    int o = blockIdx.x;
    int t = threadIdx.x;
    float b[R];
#pragma unroll
    for (int r = 0; r < R; ++r) b[r] = lB[o * R + r];
#pragma unroll
    for (int c = 0; c < 4; ++c) {
        int i = c * 1024 + t * 4;
        float4 wv = *reinterpret_cast<const float4*>(&W[o * K + i]);
        float sx = 0.f, sy = 0.f, sz = 0.f, sw = 0.f;
#pragma unroll
        for (int r = 0; r < R; ++r) {
            float4 a = *reinterpret_cast<const float4*>(&lA[r * K + i]);
            sx += b[r] * a.x; sy += b[r] * a.y;
            sz += b[r] * a.z; sw += b[r] * a.w;
        }
        u16x4 ov = { f2bf(wv.x + S * sx), f2bf(wv.y + S * sy),
                     f2bf(wv.z + S * sz), f2bf(wv.w + S * sw) };
        *reinterpret_cast<u16x4*>(&out[o * K + i]) = ov;
    }
}

// ---------------- main GEMM: 256x256 tile, 8-wave, 16x16x32 MFMA ----------------
// LDS (x2 dbuf): A tile 256x64 bf16 [0,32768) + B tile [32768,65536) per buf,
// 128B rows, XOR-swizzled: phys = row*128 + (colbyte ^ ((row&7)<<4)).
// Stage linear via global_load_lds with lane-pre-swizzled global source.
#define STAGE(G, h, tt, bsel, moff)                                           \
    do {                                                                      \
        const unsigned short* g0 = (G) +                                      \
            (size_t)((h) * 128 + wid * 16 + rc) * K_DIM + (tt) * 64 + cc * 8; \
        char* l0 = lds + (bsel) * 65536 + (moff) + (h) * 16384 + wid * 2048;  \
        async16(g0, l0);                                                      \
        async16(g0 + 8 * K_DIM, l0 + 1024);                                   \
    } while (0)

#define LDA(mh, bsel)                                                         \
    _Pragma("unroll") for (int mm = 0; mm < 4; ++mm)                          \
    _Pragma("unroll") for (int ks = 0; ks < 2; ++ks)                          \
        ar[mm][ks] = *(const bf16x8*)(lds + (bsel) * 65536 +                  \
            ((aBase + ((mh) * 4 + mm) * 2048) ^ (ks << 6)));

#define LDB(nh, bsel)                                                         \
    _Pragma("unroll") for (int nn = 0; nn < 2; ++nn)                          \
    _Pragma("unroll") for (int ks = 0; ks < 2; ++ks)                          \
        br[(nh) * 2 + nn][ks] = *(const bf16x8*)(lds + (bsel) * 65536 +       \
            ((bBase + ((nh) * 2 + nn) * 2048) ^ (ks << 6)));

#define MM(mh, nh)                                                            \
    _Pragma("unroll") for (int ks = 0; ks < 2; ++ks)                          \
    _Pragma("unroll") for (int mm = 0; mm < 4; ++mm)                          \
    _Pragma("unroll") for (int nn = 0; nn < 2; ++nn)                          \
        acc[(mh) * 4 + mm][(nh) * 2 + nn] =                                   \
            __builtin_amdgcn_mfma_f32_16x16x32_bf16(                          \
                ar[mm][ks], br[(nh) * 2 + nn][ks],                            \
                acc[(mh) * 4 + mm][(nh) * 2 + nn], 0, 0, 0);

#define PHASE_MID()                                                           \
    __builtin_amdgcn_s_barrier();                                             \
    asm volatile("s_waitcnt lgkmcnt(0)" ::: "memory");                        \
    __builtin_amdgcn_s_setprio(1)

__global__ void __launch_bounds__(512, 2) gemm8p_kernel(
    const unsigned short* __restrict__ A,
    const unsigned short* __restrict__ B,
    const float* __restrict__ bias,
    float* __restrict__ C) {
    __shared__ __align__(1024) char lds[131072];

    const int tid = threadIdx.x;
    const int lane = tid & 63, wid = tid >> 6;
    const int wm = wid >> 2, wn = wid & 3;   // 2 x 4 waves
    const int lr = lane & 15, lg = lane >> 4;

    // persistent quad mapping: 256 blocks = 32 qm x 8 qn; XCD = bid%8 = qn
    // -> each XCD works one bn-pair (B quad-panel 4MB = its L2).
    const int bid = blockIdx.x;
    const int qm = bid >> 3, qn = bid & 7;
    // zigzag tile order: shares A panel at tau0->1 and 2->3, B panel at 1->2.
    const int bmArr[4] = { 2 * qm, 2 * qm, 2 * qm + 1, 2 * qm + 1 };
    const int bnArr[4] = { 2 * qn, 2 * qn + 1, 2 * qn + 1, 2 * qn };
    const unsigned short* AgArr[4];
    const unsigned short* BgArr[4];
#pragma unroll
    for (int i = 0; i < 4; ++i) {
        AgArr[i] = A + (size_t)bmArr[i] * 256 * K_DIM;
        BgArr[i] = B + (size_t)bnArr[i] * 256 * K_DIM;
    }

    // staging lane pre-swizzle (inverse of the read XOR)
    const int lam = lane ^ (lane >> 3);
    const int rc = lam >> 3, cc = lam & 7;

    // read-side swizzled bases (round-2 pattern: measured conflict-free)
    const int kx0 = (lg * 16) ^ ((lr & 7) << 4);
    const int aBase = (wm * 128 + lr) * 128 + kx0;
    const int bBase = 32768 + (wn * 64 + lr) * 128 + kx0;

    bf16x8 ar[4][2], br[4][2];

    // prologue (tile 0): t0.B0, t0.B1, t0.A0, t0.A1, t1.B0, t1.B1
    STAGE(BgArr[0], 0, 0, 0, 32768);
    STAGE(BgArr[0], 1, 0, 0, 32768);
    STAGE(AgArr[0], 0, 0, 0, 0);
    STAGE(AgArr[0], 1, 0, 0, 0);
    STAGE(BgArr[0], 0, 1, 1, 32768);
    STAGE(BgArr[0], 1, 1, 1, 32768);
    asm volatile("s_waitcnt vmcnt(4)" ::: "memory");
    __builtin_amdgcn_s_barrier();

#pragma unroll
    for (int tau = 0; tau < 4; ++tau) {
        const int nx = (tau < 3) ? tau + 1 : 3;
        const unsigned short* AgC = AgArr[tau];
        const unsigned short* AgN = AgArr[nx];
        const unsigned short* BgC = BgArr[tau];
        const unsigned short* BgN = BgArr[nx];

        f32x4 acc[8][4] = {};

#pragma unroll 2
        for (int t = 0; t < NT; ++t) {
            const int bs = t & 1, bo = bs ^ 1;
            const unsigned short* As = (t < NT - 1) ? AgC : AgN;
            const unsigned short* Bs = (t < NT - 2) ? BgC : BgN;
            const int ta = (t + 1) & 63;
            const int tb = (t + 2) & 63;
            const bool doA = (tau < 3) || (t < NT - 1);
            const bool doB = (tau < 3) || (t < NT - 2);
            // ---- phase 0: (0,0). END-0 dropped (verified r3<->r4).
            LDA(0, bs);
            LDB(0, bs);
            if (doA) STAGE(As, 0, ta, bo, 0);
            PHASE_MID();
            MM(0, 0);
            __builtin_amdgcn_s_setprio(0);
            // ---- phase 1: (0,1). END-1 REQUIRED (phase-2 restages bs.B[0:128)).
            LDB(1, bs);
            if (doA) STAGE(As, 1, ta, bo, 0);
            PHASE_MID();
            MM(0, 1);
            __builtin_amdgcn_s_setprio(0);
            __builtin_amdgcn_s_barrier();
            // ---- phase 2: (1,0). END-2 dropped.
            LDA(1, bs);
            if (doB) STAGE(Bs, 0, tb, bs, 32768);
            PHASE_MID();
            MM(1, 0);
            __builtin_amdgcn_s_setprio(0);
            // ---- phase 3: (1,1) + boundary counted vmcnt
            if (doB) STAGE(Bs, 1, tb, bs, 32768);
            PHASE_MID();
            MM(1, 1);
            __builtin_amdgcn_s_setprio(0);
            if (doB) {
                asm volatile("s_waitcnt vmcnt(4)" ::: "memory");
            } else {
                asm volatile("s_waitcnt vmcnt(0)" ::: "memory");
            }
            __builtin_amdgcn_s_barrier();
        }

        // epilogue tile tau (no LDS access; next tile's t0/t1 already staged)
        const int row0 = bmArr[tau] * 256 + wm * 128;
        const int col0 = bnArr[tau] * 256 + wn * 64;
#pragma unroll
        for (int n = 0; n < 4; ++n) {
            const int col = col0 + n * 16 + lr;
            const float bv = bias[col];
#pragma unroll
            for (int m = 0; m < 8; ++m) {
                const int r0 = row0 + m * 16 + lg * 4;
#pragma unroll
                for (int r = 0; r < 4; ++r)
                    C[(size_t)(r0 + r) * N_DIM + col] = acc[m][n][r] + bv;
            }
        }
    }
}

extern "C" void kernel_launch(void* const* d_in, const int* in_sizes, int n_in,
                              void* d_out, int out_size, void* d_ws, size_t ws_size,
                              hipStream_t stream) {
    const float* x    = (const float*)d_in[0];  // [4,4096,4096]
    const float* W    = (const float*)d_in[1];  // [4096,4096]
    const float* bias = (const float*)d_in[2];  // [4096]
    const float* lA   = (const float*)d_in[3];  // [16,4096]
    const float* lB   = (const float*)d_in[4];  // [4096,16]
    float* out = (float*)d_out;

    unsigned short* xb   = (unsigned short*)d_ws;                       // 134 MB
    unsigned short* weff = (unsigned short*)((char*)d_ws + 134217728);  // 32 MB

    cast_x_kernel<<<2048, 256, 0, stream>>>((const float4*)x, (u16x4*)xb,
                                            M_DIM * K_DIM / 4);
    weff_kernel<<<N_DIM, 256, 0, stream>>>(W, lA, lB, weff);
    gemm8p_kernel<<<256, 512, 0, stream>>>(xb, weff, bias, out);
}

// Round 6
// 590.513 us; speedup vs baseline: 1.1555x; 1.1555x over previous
//
#include <hip/hip_runtime.h>
#include <hip/hip_bf16.h>

// LoRALinear: out = x @ (W + 2.0*B@A)^T + bias ; M=16384, N=4096, K=4096, R=16.
// Round 6: 2-barrier K-loop. Round-5 post-mortem: phase skeleton serialized
// LDS-read wall (2304 cyc/K-tile) with MFMA wall (2483 cyc) -> 4828 measured.
// Fix: issue fragment reads early, let compiler emit counted lgkmcnt so reads
// drain UNDER MFMA; keep only the 2 provably-required barriers per K-tile
// (END-1 = B-restage hazard; boundary = dbuf flip w/ counted vmcnt(4)).
// Grid/mapping reverted to round-2 exact (persistence hurt L2: FETCH 2x).
// ws layout: [0,134217728) x_bf16 ; [134217728, +33554432) W_eff_bf16.

typedef __attribute__((ext_vector_type(8))) short bf16x8;
typedef __attribute__((ext_vector_type(4))) float f32x4;
typedef __attribute__((ext_vector_type(4))) unsigned short u16x4;

#define M_DIM 16384
#define N_DIM 4096
#define K_DIM 4096
#define NT 64   // K-tiles of BK=64

__device__ __forceinline__ unsigned short f2bf(float f) {
    unsigned int u = __builtin_bit_cast(unsigned int, f);
    unsigned int r = u + 0x7FFFu + ((u >> 16) & 1u);
    return (unsigned short)(r >> 16);
}

__device__ __forceinline__ void async16(const void* g, void* l) {
    __builtin_amdgcn_global_load_lds(
        (const __attribute__((address_space(1))) unsigned int*)g,
        (__attribute__((address_space(3))) unsigned int*)l,
        16, 0, 0);
}

// ---------------- prep kernel 1: x fp32 -> bf16 ----------------
__global__ void __launch_bounds__(256) cast_x_kernel(
    const float4* __restrict__ x, u16x4* __restrict__ y, int n4) {
    int i = blockIdx.x * blockDim.x + threadIdx.x;
    int stride = gridDim.x * blockDim.x;
    for (; i < n4; i += stride) {
        float4 v = x[i];
        u16x4 o = { f2bf(v.x), f2bf(v.y), f2bf(v.z), f2bf(v.w) };
        y[i] = o;
    }
}

// ---------------- prep kernel 2: W_eff = W + 2*B@A -> bf16 ----------------
__global__ void __launch_bounds__(256) weff_kernel(
    const float* __restrict__ W, const float* __restrict__ lA,
    const float* __restrict__ lB, unsigned short* __restrict__ out) {
    constexpr int K = K_DIM, R = 16;
    constexpr float S = 2.0f;  // 32.0 / 16
    int o = blockIdx.x;
    int t = threadIdx.x;
    float b[R];
#pragma unroll
    for (int r = 0; r < R; ++r) b[r] = lB[o * R + r];
#pragma unroll
    for (int c = 0; c < 4; ++c) {
        int i = c * 1024 + t * 4;
        float4 wv = *reinterpret_cast<const float4*>(&W[o * K + i]);
        float sx = 0.f, sy = 0.f, sz = 0.f, sw = 0.f;
#pragma unroll
        for (int r = 0; r < R; ++r) {
            float4 a = *reinterpret_cast<const float4*>(&lA[r * K + i]);
            sx += b[r] * a.x; sy += b[r] * a.y;
            sz += b[r] * a.z; sw += b[r] * a.w;
        }
        u16x4 ov = { f2bf(wv.x + S * sx), f2bf(wv.y + S * sy),
                     f2bf(wv.z + S * sz), f2bf(wv.w + S * sw) };
        *reinterpret_cast<u16x4*>(&out[o * K + i]) = ov;
    }
}

// ---------------- main GEMM: 256x256 tile, 8-wave, 16x16x32 MFMA ----------------
// LDS (x2 dbuf): A tile 256x64 bf16 [0,32768) + B tile [32768,65536) per buf,
// 128B rows, XOR-swizzled: phys = row*128 + (colbyte ^ ((row&7)<<4)).
// Stage linear via global_load_lds with lane-pre-swizzled global source.
#define STAGE(G, h, tt, bsel, moff)                                           \
    do {                                                                      \
        const unsigned short* g0 = (G) +                                      \
            (size_t)((h) * 128 + wid * 16 + rc) * K_DIM + (tt) * 64 + cc * 8; \
        char* l0 = lds + (bsel) * 65536 + (moff) + (h) * 16384 + wid * 2048;  \
        async16(g0, l0);                                                      \
        async16(g0 + 8 * K_DIM, l0 + 1024);                                   \
    } while (0)

// fragment reads (round-2 pattern: measured 0 bank conflicts)
#define LDA_TO(dst, mh, bsel)                                                 \
    _Pragma("unroll") for (int mm = 0; mm < 4; ++mm)                          \
    _Pragma("unroll") for (int ks = 0; ks < 2; ++ks)                          \
        dst[mm][ks] = *(const bf16x8*)(lds + (bsel) * 65536 +                 \
            ((aBase + ((mh) * 4 + mm) * 2048) ^ (ks << 6)));

#define LDB_TO(nh, bsel)                                                      \
    _Pragma("unroll") for (int nn = 0; nn < 2; ++nn)                          \
    _Pragma("unroll") for (int ks = 0; ks < 2; ++ks)                          \
        br[(nh) * 2 + nn][ks] = *(const bf16x8*)(lds + (bsel) * 65536 +       \
            ((bBase + ((nh) * 2 + nn) * 2048) ^ (ks << 6)));

// one output quadrant: 16 MFMA using A-set `src` (mh) x B half (nh)
#define MM_Q(src, mh, nh)                                                     \
    __builtin_amdgcn_s_setprio(1);                                            \
    _Pragma("unroll") for (int ks = 0; ks < 2; ++ks)                          \
    _Pragma("unroll") for (int mm = 0; mm < 4; ++mm)                          \
    _Pragma("unroll") for (int nn = 0; nn < 2; ++nn)                          \
        acc[(mh) * 4 + mm][(nh) * 2 + nn] =                                   \
            __builtin_amdgcn_mfma_f32_16x16x32_bf16(                          \
                src[mm][ks], br[(nh) * 2 + nn][ks],                           \
                acc[(mh) * 4 + mm][(nh) * 2 + nn], 0, 0, 0);                  \
    __builtin_amdgcn_s_setprio(0)

#define CFENCE() asm volatile("" ::: "memory")

__global__ void __launch_bounds__(512, 2) gemm2b_kernel(
    const unsigned short* __restrict__ A,
    const unsigned short* __restrict__ B,
    const float* __restrict__ bias,
    float* __restrict__ C) {
    __shared__ __align__(1024) char lds[131072];

    const int tid = threadIdx.x;
    const int lane = tid & 63, wid = tid >> 6;
    const int wm = wid >> 2, wn = wid & 3;   // 2 x 4 waves
    const int lr = lane & 15, lg = lane >> 4;

    // round-2 mapping: 1024 blocks, XCD-aware swizzle
    const int bid = blockIdx.x;
    const int swz = (bid & 7) * 128 + (bid >> 3);
    const int bm = swz >> 4, bn = swz & 15;  // 64 x 16 tiles

    const unsigned short* Ag = A + (size_t)bm * 256 * K_DIM;
    const unsigned short* Bg = B + (size_t)bn * 256 * K_DIM;

    // staging lane pre-swizzle (inverse of the read XOR)
    const int lam = lane ^ (lane >> 3);
    const int rc = lam >> 3, cc = lam & 7;

    // read-side swizzled bases
    const int kx0 = (lg * 16) ^ ((lr & 7) << 4);
    const int aBase = (wm * 128 + lr) * 128 + kx0;
    const int bBase = 32768 + (wn * 64 + lr) * 128 + kx0;

    f32x4 acc[8][4] = {};
    bf16x8 arA[4][2], arB[4][2], br[4][2];

    // prologue: B(0), A(0) -> buf0 ; B(1) -> buf1
    STAGE(Bg, 0, 0, 0, 32768);
    STAGE(Bg, 1, 0, 0, 32768);
    STAGE(Ag, 0, 0, 0, 0);
    STAGE(Ag, 1, 0, 0, 0);
    STAGE(Bg, 0, 1, 1, 32768);
    STAGE(Bg, 1, 1, 1, 32768);
    asm volatile("s_waitcnt vmcnt(4)" ::: "memory");
    __builtin_amdgcn_s_barrier();
    CFENCE();

#pragma unroll 2
    for (int t = 0; t < NT; ++t) {
        const int bs = t & 1, bo = bs ^ 1;
        // --- early fragment reads: RA0 (arA), RB0+RB1 (br). Compiler emits
        // counted lgkmcnt before each consuming MFMA; reads drain under MFMA.
        LDA_TO(arA, 0, bs);
        LDB_TO(0, bs);
        LDB_TO(1, bs);
        // A(t+1) staging (writes bo.A — no reader until after next boundary)
        if (t + 1 < NT) {
            STAGE(Ag, 0, t + 1, bo, 0);
            STAGE(Ag, 1, t + 1, bo, 0);
        }
        MM_Q(arA, 0, 0);
        // RA1 into second A set; drains under MFMA(0,0)/(0,1)
        LDA_TO(arB, 1, bs);
        MM_Q(arA, 0, 1);
        // --- END-1 barrier: every wave consumed br (MFMA(0,1)) before here;
        // B(t+2) STAGEs below overwrite bs.B — cross-wave hazard closed.
        CFENCE();
        __builtin_amdgcn_s_barrier();
        CFENCE();
        if (t + 2 < NT) STAGE(Bg, 0, t + 2, bs, 32768);
        MM_Q(arB, 1, 0);
        if (t + 2 < NT) STAGE(Bg, 1, t + 2, bs, 32768);
        MM_Q(arB, 1, 1);
        // --- boundary: counted vmcnt retires A(t+1)+B(t+1); barrier flips dbuf
        if (t < NT - 2) {
            asm volatile("s_waitcnt vmcnt(4)" ::: "memory");
        } else {
            asm volatile("s_waitcnt vmcnt(0)" ::: "memory");
        }
        __builtin_amdgcn_s_barrier();
        CFENCE();
    }

    // epilogue: D col = lane&15, row = (lane>>4)*4 + r (verified m89/m91)
    const int row0 = bm * 256 + wm * 128;
    const int col0 = bn * 256 + wn * 64;
#pragma unroll
    for (int n = 0; n < 4; ++n) {
        const int col = col0 + n * 16 + lr;
        const float bv = bias[col];
#pragma unroll
        for (int m = 0; m < 8; ++m) {
            const int r0 = row0 + m * 16 + lg * 4;
#pragma unroll
            for (int r = 0; r < 4; ++r)
                C[(size_t)(r0 + r) * N_DIM + col] = acc[m][n][r] + bv;
        }
    }
}

extern "C" void kernel_launch(void* const* d_in, const int* in_sizes, int n_in,
                              void* d_out, int out_size, void* d_ws, size_t ws_size,
                              hipStream_t stream) {
    const float* x    = (const float*)d_in[0];  // [4,4096,4096]
    const float* W    = (const float*)d_in[1];  // [4096,4096]
    const float* bias = (const float*)d_in[2];  // [4096]
    const float* lA   = (const float*)d_in[3];  // [16,4096]
    const float* lB   = (const float*)d_in[4];  // [4096,16]
    float* out = (float*)d_out;

    unsigned short* xb   = (unsigned short*)d_ws;                       // 134 MB
    unsigned short* weff = (unsigned short*)((char*)d_ws + 134217728);  // 32 MB

    cast_x_kernel<<<2048, 256, 0, stream>>>((const float4*)x, (u16x4*)xb,
                                            M_DIM * K_DIM / 4);
    weff_kernel<<<N_DIM, 256, 0, stream>>>(W, lA, lB, weff);
    gemm2b_kernel<<<(M_DIM / 256) * (N_DIM / 256), 512, 0, stream>>>(
        xb, weff, bias, out);
}